// Round 6
// baseline (580.728 us; speedup 1.0000x reference)
//
#include <hip/hip_runtime.h>
#include <hip/hip_bf16.h>
#include <cstdint>
#include <cstddef>

typedef float f32x4 __attribute__((ext_vector_type(4)));
typedef __bf16 bf16x8v __attribute__((ext_vector_type(8)));
typedef __hip_bfloat16 bf16;

// async global->LDS, 16 B per lane (lds ptr: wave-uniform base + lane*16)
__device__ __forceinline__ void gld16(const void* g, void* l) {
  __builtin_amdgcn_global_load_lds((const __attribute__((address_space(1))) void*)g,
                                   (__attribute__((address_space(3))) void*)l, 16, 0, 0);
}

// ---------------- prep: weights->bf16(Kpad), zero accs, geo->bf16(ld576), batch offsets ----
// cnt layout: cnt[0..8] = src batch start offsets (cnt[8]=Ns), cnt[9..17] = tgt starts

struct PrepP {
  const float* Wsrc[6];
  bf16* Wdst[6];
  int sld[6], rows[6], K[6], Kpad[6];
  int off[10];            // block-range starts: jobs 0..5 weights, 6 zero, 7 geo_b, 8 maps; off[9]=end
  float* zbuf; int ztotal;
  const float* geo; bf16* geo_b; int Nrows;
  const int* sics; const int* tics; int Ns, Nt; int* cnt;
};

__global__ void prep_kernel(PrepP P) {
  int blk = blockIdx.x;
  int job = 0;
  while (job < 8 && blk >= P.off[job + 1]) ++job;
  int local = blk - P.off[job];
  if (job < 6) {
    int i = local * 256 + threadIdx.x;
    int kp = P.Kpad[job];
    int total = P.rows[job] * kp;
    if (i < total) {
      int r = i / kp, k = i - r * kp;
      float v = (k < P.K[job]) ? P.Wsrc[job][(size_t)r * P.sld[job] + k] : 0.f;
      P.Wdst[job][i] = __float2bfloat16(v);
    }
  } else if (job == 6) {
    int i = local * 256 + threadIdx.x;
    if (i < P.ztotal) P.zbuf[i] = 0.f;
  } else if (job == 7) {
    int t = local * 256 + threadIdx.x;
    int row = t / 72, c8 = t - row * 72;
    if (row < P.Nrows) {
      int col = c8 * 8;
      bf16* dst = P.geo_b + (size_t)row * 576 + col;
      if (c8 < 66) {
        const float* s = P.geo + (size_t)row * 528 + col;
        float4 f0 = ((const float4*)s)[0], f1 = ((const float4*)s)[1];
        bf16 h[8] = {__float2bfloat16(f0.x), __float2bfloat16(f0.y),
                     __float2bfloat16(f0.z), __float2bfloat16(f0.w),
                     __float2bfloat16(f1.x), __float2bfloat16(f1.y),
                     __float2bfloat16(f1.z), __float2bfloat16(f1.w)};
        ((uint4*)dst)[0] = *(uint4*)h;
      } else {
        uint4 z = {0u, 0u, 0u, 0u};
        ((uint4*)dst)[0] = z;      // K-pad cols 528..575
      }
    }
  } else {  // maps: batch start offsets, atomic-free
    int j = local * 256 + threadIdx.x;
    if (j < P.Ns) {
      if (j == 0) { P.cnt[0] = 0; P.cnt[8] = P.Ns; }
      else { int b = P.sics[j] >> 12; if ((P.sics[j - 1] >> 12) != b) P.cnt[b] = j; }
    }
    if (j < P.Nt) {
      if (j == 0) { P.cnt[9] = 0; P.cnt[17] = P.Nt; }
      else { int b = P.tics[j] >> 12; if ((P.tics[j - 1] >> 12) != b) P.cnt[9 + b] = j; }
    }
  }
}

// ---------------- GEMM core: 128x128 tile, BK=64 via twin 128x32 LDS buffers ----------------
// 8 outstanding global_load_lds, 32 MFMA per barrier pair.
__device__ __forceinline__ void gemm_core(
    const bf16* __restrict__ Aptr, int lda,
    const bf16* __restrict__ Bw, int ldb,
    int m0, int n0, int kiters,
    bf16* __restrict__ lA, bf16* __restrict__ lB,
    f32x4 acc[4][4])
{
  const int tid  = threadIdx.x;
  const int lane = tid & 63;
  const int quad = lane >> 4;
  const int l16  = lane & 15;
  const int wr   = tid >> 7;
  const int wc   = (tid >> 6) & 1;
  const int srow = tid >> 2;
  const int scol = (tid & 3) << 3;
  const bf16* aA0 = Aptr + (size_t)(m0 + srow) * lda + scol;
  const bf16* aA1 = aA0 + (size_t)64 * lda;
  const bf16* aB0 = Bw + (size_t)(n0 + srow) * ldb + scol;
  const bf16* aB1 = aB0 + (size_t)64 * ldb;
  bf16* lA00 = lA + tid * 8;        bf16* lA01 = lA + 2048 + tid * 8;
  bf16* lA10 = lA + 4096 + tid * 8; bf16* lA11 = lA + 6144 + tid * 8;
  bf16* lB00 = lB + tid * 8;        bf16* lB01 = lB + 2048 + tid * 8;
  bf16* lB10 = lB + 4096 + tid * 8; bf16* lB11 = lB + 6144 + tid * 8;

  for (int k = 0; k < kiters; ++k) {
    const int k0 = k * 64;
    gld16(aA0 + k0, lA00);      gld16(aA1 + k0, lA01);
    gld16(aA0 + k0 + 32, lA10); gld16(aA1 + k0 + 32, lA11);
    gld16(aB0 + k0, lB00);      gld16(aB1 + k0, lB01);
    gld16(aB0 + k0 + 32, lB10); gld16(aB1 + k0 + 32, lB11);
    __syncthreads();
#pragma unroll
    for (int kk = 0; kk < 2; ++kk) {
      bf16x8v af[4], bfr[4];
#pragma unroll
      for (int i = 0; i < 4; ++i) {
        af[i]  = *(const bf16x8v*)&lA[kk * 4096 + (wr * 64 + i * 16 + l16) * 32 + quad * 8];
        bfr[i] = *(const bf16x8v*)&lB[kk * 4096 + (wc * 64 + i * 16 + l16) * 32 + quad * 8];
      }
#pragma unroll
      for (int mi = 0; mi < 4; ++mi)
#pragma unroll
        for (int ni = 0; ni < 4; ++ni)
          acc[mi][ni] = __builtin_amdgcn_mfma_f32_16x16x32_bf16(af[mi], bfr[ni], acc[mi][ni], 0, 0, 0);
    }
    __syncthreads();
  }
}

// ---------------- kernel A: GEMM1 (src L1) + GEMM3 (tgt L1) + GEMM5-pre (z w/o glob) ------
__global__ __launch_bounds__(256, 2)
void kernelA(const bf16* __restrict__ geo_b,
             const bf16* __restrict__ Wi1b, const bf16* __restrict__ Wc1b,
             const bf16* __restrict__ Ws1sb,
             const float* __restrict__ bi1, const float* __restrict__ bc1,
             bf16* __restrict__ big_s, bf16* __restrict__ big_t,
             bf16* __restrict__ zpre, int Ms, int Mt)
{
  __shared__ alignas(16) bf16 lA[8192], lB[8192];
  const int x = blockIdx.x;
  const int e0 = Ms * 5, e1 = e0 + Mt * 5;
  const bf16 *A, *B; const float* bias = nullptr; bf16* out;
  int m0, n0, ldo, epi;
  if (x < e0) {
    int mt = x / 5, nt = x - mt * 5;
    m0 = mt * 128; n0 = nt * 128;
    A = geo_b; B = Wi1b; bias = bi1; out = big_s; ldo = 576; epi = 0;
  } else if (x < e1) {
    int y = x - e0; int mt = y / 5, nt = y - mt * 5;
    m0 = mt * 128; n0 = nt * 128;
    A = geo_b + (size_t)Ms * 128 * 576; B = Wc1b; bias = bc1; out = big_t; ldo = 576; epi = 0;
  } else {
    int y = x - e1; int mt = y / 4, nt = y - mt * 4;
    m0 = mt * 128; n0 = nt * 128;
    A = geo_b; B = Ws1sb; out = zpre; ldo = 512; epi = 1;
  }

  f32x4 acc[4][4];
  const f32x4 z4 = {0.f, 0.f, 0.f, 0.f};
#pragma unroll
  for (int i = 0; i < 4; ++i)
#pragma unroll
    for (int j = 0; j < 4; ++j) acc[i][j] = z4;

  gemm_core(A, 576, B, 576, m0, n0, 9, lA, lB, acc);

  const int lane = threadIdx.x & 63, quad = lane >> 4, l16 = lane & 15;
  const int wr = threadIdx.x >> 7, wc = (threadIdx.x >> 6) & 1;
#pragma unroll
  for (int mi = 0; mi < 4; ++mi) {
#pragma unroll
    for (int r = 0; r < 4; ++r) {
      const int row = m0 + wr * 64 + mi * 16 + quad * 4 + r;
#pragma unroll
      for (int ni = 0; ni < 4; ++ni) {
        const int col = n0 + wc * 64 + ni * 16 + l16;
        if (epi == 0) {
          if (col < 528)
            out[(size_t)row * ldo + col] = __float2bfloat16(fmaxf(acc[mi][ni][r] + bias[col], 0.f));
          else if (col < 576)
            out[(size_t)row * ldo + col] = __float2bfloat16(0.f);
        } else {
          out[(size_t)row * ldo + col] = __float2bfloat16(acc[mi][ni][r]);  // z_pre, raw
        }
      }
    }
  }
}

// ---------------- kernel B: GEMM2 + GEMM4, 128x256 per block (A staged once for 2 N-tiles) --
// Halves A-panel HBM demand vs 128x128; 64 MFMA per barrier pair. Fill jobs at grid tail.
__global__ __launch_bounds__(256, 2)
void kernelB(const bf16* __restrict__ big_s, const bf16* __restrict__ big_t,
             const bf16* __restrict__ Wi2b, const bf16* __restrict__ Wc2b,
             const float* __restrict__ bi2, const float* __restrict__ bc2,
             float* __restrict__ iacc, float* __restrict__ cacc,
             const int* __restrict__ sics, const int* __restrict__ tics,
             int Ms, int Mt,
             const float* __restrict__ geo, const float* __restrict__ pcd,
             const int* __restrict__ cnt,
             float* __restrict__ out0, float* __restrict__ out1,
             float* __restrict__ out2, float* __restrict__ out3,
             int Ns, float inv)
{
  __shared__ alignas(16) bf16 lA[8192], lB[16384];
  const int x = blockIdx.x;
  const int e0 = Ms * 4, e1 = e0 + Mt * 4;
  if (x >= e1) {
    // -------- fill job: 4 output rows per block, 64 lanes/row --------
    int f = x - e1;
    int lane = threadIdx.x & 63;
    int rv = f * 4 + (threadIdx.x >> 6);       // 0..65535
    bool is_t = rv >= 32768;
    int pos = is_t ? rv - 32768 : rv;
    int b = pos >> 12, r = pos & 4095;
    int base = is_t ? cnt[9 + b] : cnt[b];
    int lim  = (is_t ? cnt[9 + b + 1] : cnt[b + 1]) - base;
    float* op = (is_t ? out1 : out0) + (size_t)pos * 528;
    float* pp = (is_t ? out3 : out2) + (size_t)pos * 3;
    if (r < lim) {
      int sr = (is_t ? Ns : 0) + base + r;
      const float4* g = (const float4*)(geo + (size_t)sr * 528);
      for (int d = lane; d < 132; d += 64) {
        float4 v = g[d];
        float4 s = {v.x * inv, v.y * inv, v.z * inv, v.w * inv};
        ((float4*)op)[d] = s;
      }
      if (lane < 3) pp[lane] = pcd[(size_t)sr * 3 + lane];
    } else {
      float4 z = {0.f, 0.f, 0.f, 0.f};
      for (int d = lane; d < 132; d += 64) ((float4*)op)[d] = z;
      if (lane < 3) pp[lane] = 0.f;
    }
    return;
  }
  // -------- GEMM job: 128 rows x 256 cols --------
  const bf16 *A, *B; const float* bias; float* red; const int* ridx;
  int m0, n0;
  if (x < e0) {
    int mt = x >> 2, g = x & 3;
    m0 = mt * 128; n0 = g * 256;
    A = big_s; B = Wi2b; bias = bi2; red = iacc; ridx = sics;
  } else {
    int y = x - e0; int mt = y >> 2, g = y & 3;
    m0 = mt * 128; n0 = g * 256;
    A = big_t; B = Wc2b; bias = bc2; red = cacc; ridx = tics;
  }

  const int tid  = threadIdx.x;
  const int lane = tid & 63, quad = lane >> 4, l16 = lane & 15;
  const int wr = tid >> 7, wc = (tid >> 6) & 1;
  const int srow = tid >> 2;
  const int scol = (tid & 3) << 3;
  const bf16* aA0 = A + (size_t)(m0 + srow) * 576 + scol;
  const bf16* aA1 = aA0 + (size_t)64 * 576;
  const bf16* aB0 = B + (size_t)(n0 + srow) * 576 + scol;   // tile0 rows n0..n0+127
  const bf16* aB1 = aB0 + (size_t)64 * 576;
  const bf16* aB2 = aB0 + (size_t)128 * 576;                // tile1 rows n0+128..n0+255
  const bf16* aB3 = aB0 + (size_t)192 * 576;

  f32x4 acc[4][8];   // [mi][t*4+ni]
  const f32x4 z4 = {0.f, 0.f, 0.f, 0.f};
#pragma unroll
  for (int i = 0; i < 4; ++i)
#pragma unroll
    for (int j = 0; j < 8; ++j) acc[i][j] = z4;

  for (int k = 0; k < 9; ++k) {
    const int k0 = k * 64;
    gld16(aA0 + k0, lA + tid * 8);           gld16(aA1 + k0, lA + 2048 + tid * 8);
    gld16(aA0 + k0 + 32, lA + 4096 + tid * 8); gld16(aA1 + k0 + 32, lA + 6144 + tid * 8);
    gld16(aB0 + k0, lB + tid * 8);           gld16(aB1 + k0, lB + 2048 + tid * 8);
    gld16(aB0 + k0 + 32, lB + 4096 + tid * 8); gld16(aB1 + k0 + 32, lB + 6144 + tid * 8);
    gld16(aB2 + k0, lB + 8192 + tid * 8);    gld16(aB3 + k0, lB + 10240 + tid * 8);
    gld16(aB2 + k0 + 32, lB + 12288 + tid * 8); gld16(aB3 + k0 + 32, lB + 14336 + tid * 8);
    __syncthreads();
#pragma unroll
    for (int kk = 0; kk < 2; ++kk) {
      bf16x8v af[4], bf0[4], bf1[4];
#pragma unroll
      for (int i = 0; i < 4; ++i) {
        const int ro = (wc * 64 + i * 16 + l16) * 32 + quad * 8;
        af[i]  = *(const bf16x8v*)&lA[kk * 4096 + (wr * 64 + i * 16 + l16) * 32 + quad * 8];
        bf0[i] = *(const bf16x8v*)&lB[kk * 4096 + ro];
        bf1[i] = *(const bf16x8v*)&lB[8192 + kk * 4096 + ro];
      }
#pragma unroll
      for (int mi = 0; mi < 4; ++mi)
#pragma unroll
        for (int ni = 0; ni < 4; ++ni) {
          acc[mi][ni]     = __builtin_amdgcn_mfma_f32_16x16x32_bf16(af[mi], bf0[ni], acc[mi][ni], 0, 0, 0);
          acc[mi][4 + ni] = __builtin_amdgcn_mfma_f32_16x16x32_bf16(af[mi], bf1[ni], acc[mi][4 + ni], 0, 0, 0);
        }
    }
    __syncthreads();
  }

  // per-batch column sums (rows batch-sorted; 128-row tile spans <=2 batches)
  const int b0r = ridx[m0] >> 12;
#pragma unroll
  for (int t = 0; t < 2; ++t) {
#pragma unroll
    for (int ni = 0; ni < 4; ++ni) {
      const int col = n0 + t * 128 + wc * 64 + ni * 16 + l16;
      const float bcol = bias[col];
#pragma unroll
      for (int mi = 0; mi < 4; ++mi) {
        float v0 = 0.f, v1 = 0.f;
#pragma unroll
        for (int r = 0; r < 4; ++r) {
          const int row = m0 + wr * 64 + mi * 16 + quad * 4 + r;
          const float v = fmaxf(acc[mi][t * 4 + ni][r] + bcol, 0.f);
          const int b = ridx[row] >> 12;
          if (b == b0r) v0 += v; else v1 += v;
        }
        v0 += __shfl_xor(v0, 16, 64); v0 += __shfl_xor(v0, 32, 64);
        v1 += __shfl_xor(v1, 16, 64); v1 += __shfl_xor(v1, 32, 64);
        if (quad == 0) {
          atomicAdd(&red[b0r * 1024 + col], v0);
          if (b0r + 1 < 8 && v1 != 0.f) atomicAdd(&red[(b0r + 1) * 1024 + col], v1);
        }
      }
    }
  }
}

// ---------------- kernel C: GEMM6 + fused s-dot (z2 never materialized) ----------------
__global__ __launch_bounds__(256, 2)
void kernelC(const bf16* __restrict__ zpre, const bf16* __restrict__ Ws2b,
             const float* __restrict__ bs2, const float* __restrict__ Ws3,
             float* __restrict__ sbuf)
{
  __shared__ alignas(16) bf16 lA[8192], lB[8192];
  const int m0 = blockIdx.x * 128, n0 = blockIdx.y * 128;
  f32x4 acc[4][4];
  const f32x4 z4 = {0.f, 0.f, 0.f, 0.f};
#pragma unroll
  for (int i = 0; i < 4; ++i)
#pragma unroll
    for (int j = 0; j < 4; ++j) acc[i][j] = z4;

  gemm_core(zpre, 512, Ws2b, 512, m0, n0, 8, lA, lB, acc);

  const int lane = threadIdx.x & 63, quad = lane >> 4, l16 = lane & 15;
  const int wr = threadIdx.x >> 7, wc = (threadIdx.x >> 6) & 1;
#pragma unroll
  for (int mi = 0; mi < 4; ++mi) {
#pragma unroll
    for (int r = 0; r < 4; ++r) {
      const int row = m0 + wr * 64 + mi * 16 + quad * 4 + r;
      float p = 0.f;
#pragma unroll
      for (int ni = 0; ni < 4; ++ni) {
        const int col = n0 + wc * 64 + ni * 16 + l16;
        p += fmaxf(acc[mi][ni][r] + bs2[col], 0.f) * Ws3[col];
      }
      p += __shfl_xor(p, 1, 64); p += __shfl_xor(p, 2, 64);
      p += __shfl_xor(p, 4, 64); p += __shfl_xor(p, 8, 64);
      if (l16 == 0) atomicAdd(&sbuf[row], p);
    }
  }
}

// glob[b][o] = bs1[o] + (iacc[b]/ns) . Ws1[o,528:1552] + (cacc[b]/nt) . Ws1[o,1552:2576]
__global__ __launch_bounds__(256) void glob_kernel(const float* __restrict__ iacc,
                                                   const float* __restrict__ cacc,
                                                   const int* __restrict__ cnt,
                                                   const float* __restrict__ Ws1,
                                                   const float* __restrict__ bs1,
                                                   float* __restrict__ globv) {
  int w    = (blockIdx.x * 256 + threadIdx.x) >> 6;  // 4096 waves
  int lane = threadIdx.x & 63;
  int b = w >> 9;
  int o = w & 511;
  const float* wi  = Ws1 + (size_t)o * 2576 + 528;
  const float* wcp = Ws1 + (size_t)o * 2576 + 1552;
  float a1 = 0.f, a2 = 0.f;
  for (int k = lane; k < 1024; k += 64) {
    a1 += iacc[b * 1024 + k] * wi[k];
    a2 += cacc[b * 1024 + k] * wcp[k];
  }
  for (int off = 32; off; off >>= 1) {
    a1 += __shfl_xor(a1, off, 64);
    a2 += __shfl_xor(a2, off, 64);
  }
  if (lane == 0) {
    float ns = (float)(cnt[b + 1] - cnt[b]);
    float nt = (float)(cnt[9 + b + 1] - cnt[9 + b]);
    globv[b * 512 + o] = bs1[o] + a1 / ns + a2 / nt;
  }
}

// s value for an all-zero (invalid) row of batch b — wave-parallel, coalesced Ws2 reads.
__global__ __launch_bounds__(256) void s_empty_kernel(const float* __restrict__ globv,
                                                      const float* __restrict__ Ws2,
                                                      const float* __restrict__ bs2,
                                                      const float* __restrict__ Ws3,
                                                      const float* __restrict__ bs3,
                                                      float* __restrict__ semp) {
  __shared__ float zrow[512];
  __shared__ float wsum[4];
  int b = blockIdx.x, t = threadIdx.x;
  zrow[t]       = fmaxf(globv[b * 512 + t], 0.f);
  zrow[t + 256] = fmaxf(globv[b * 512 + t + 256], 0.f);
  __syncthreads();
  int w = t >> 6, lane = t & 63;
  float ws = 0.f;
  for (int tt = w * 64; tt < w * 64 + 64; ++tt) {
    float a = 0.f;
#pragma unroll
    for (int oi = 0; oi < 8; ++oi) {
      int o = lane + oi * 64;
      a += zrow[o] * Ws2[(size_t)tt * 512 + o];
    }
    for (int off = 32; off; off >>= 1) a += __shfl_xor(a, off, 64);
    if (lane == 0) ws += fmaxf(a + bs2[tt], 0.f) * Ws3[tt];
  }
  if (lane == 0) wsum[w] = ws;
  __syncthreads();
  if (t == 0) semp[b] = wsum[0] + wsum[1] + wsum[2] + wsum[3] + bs3[0];
}

// z = relu(z_pre + glob[b]) in-place (bf16x8 chunks)
__global__ void zfix_kernel(bf16* __restrict__ z, const float* __restrict__ globv,
                            const int* __restrict__ sics, int total) {
  int idx = blockIdx.x * 256 + threadIdx.x;
  if (idx >= total) return;                      // total = Ns*64
  int row = idx >> 6, c0 = (idx & 63) << 3;
  int b = sics[row] >> 12;
  const float* gv = globv + b * 512 + c0;
  bf16* zp = z + (size_t)row * 512 + c0;
  uint4 u = *(uint4*)zp;
  bf16* e = (bf16*)&u;
#pragma unroll
  for (int i = 0; i < 8; ++i)
    e[i] = __float2bfloat16(fmaxf(__bfloat162float(e[i]) + gv[i], 0.f));
  *(uint4*)zp = u;
}

__global__ void scale_kernel(const float* __restrict__ sbuf,
                             const float* __restrict__ semp,
                             const int* __restrict__ cnt,
                             const float* __restrict__ bs3,
                             float* __restrict__ out4) {
  int i = blockIdx.x * 256 + threadIdx.x;   // 0..32767
  if (i >= 32768) return;
  int b = i >> 12, r = i & 4095;
  int base = cnt[b];
  int lim = cnt[b + 1] - base;
  float s = (r < lim) ? sbuf[base + r] + bs3[0] : semp[b];
  out4[i] = 1.f / (1.f + expf(-s)) - 0.5f;
}

// ---------------- host ----------------

extern "C" void kernel_launch(void* const* d_in, const int* in_sizes, int n_in,
                              void* d_out, int out_size, void* d_ws, size_t ws_size,
                              hipStream_t stream) {
  const float* geo = (const float*)d_in[0];
  const float* pcd = (const float*)d_in[1];
  const float* Wi1 = (const float*)d_in[2];
  const float* bi1 = (const float*)d_in[3];
  const float* Wi2 = (const float*)d_in[4];
  const float* bi2 = (const float*)d_in[5];
  const float* Wc1 = (const float*)d_in[6];
  const float* bc1 = (const float*)d_in[7];
  const float* Wc2 = (const float*)d_in[8];
  const float* bc2 = (const float*)d_in[9];
  const float* Ws1 = (const float*)d_in[10];
  const float* bs1 = (const float*)d_in[11];
  const float* Ws2 = (const float*)d_in[12];
  const float* bs2 = (const float*)d_in[13];
  const float* Ws3 = (const float*)d_in[14];
  const float* bs3 = (const float*)d_in[15];
  const int* sics = (const int*)d_in[18];
  const int* tics = (const int*)d_in[19];
  const int Ns = in_sizes[18];   // 23552 = 184*128
  const int Nt = in_sizes[19];   // 24704 = 193*128
  const int Ms = Ns / 128, Mt = Nt / 128;
  const int Nrows = Ns + Nt;

  float* out0 = (float*)d_out;                      // (8,4096,528)
  float* out1 = out0 + (size_t)8 * 4096 * 528;      // (8,4096,528)
  float* out2 = out1 + (size_t)8 * 4096 * 528;      // (8,4096,3)
  float* out3 = out2 + (size_t)8 * 4096 * 3;        // (8,4096,3)
  float* out4 = out3 + (size_t)8 * 4096 * 3;        // (8,1,4096)

  char* wp = (char*)d_ws;
  auto alloc = [&](size_t bytes) -> void* {
    void* p = (void*)wp;
    wp += (bytes + 255) & ~(size_t)255;
    return p;
  };
  int*   cnt   = (int*)  alloc(128);
  float* iacc  = (float*)alloc((size_t)8 * 1024 * 4);   // iacc/cacc/sbuf contiguous (zero job)
  float* cacc  = (float*)alloc((size_t)8 * 1024 * 4);
  float* sbuf  = (float*)alloc((size_t)Ns * 4);
  float* globb = (float*)alloc((size_t)8 * 512 * 4);
  float* semp  = (float*)alloc(64);
  bf16* Wi1b  = (bf16*)alloc((size_t)640  * 576 * 2);   // rows 528..639 uninit (cols discarded)
  bf16* Wi2b  = (bf16*)alloc((size_t)1024 * 576 * 2);
  bf16* Wc1b  = (bf16*)alloc((size_t)640  * 576 * 2);
  bf16* Wc2b  = (bf16*)alloc((size_t)1024 * 576 * 2);
  bf16* Ws1sb = (bf16*)alloc((size_t)512  * 576 * 2);
  bf16* Ws2b  = (bf16*)alloc((size_t)256  * 512 * 2);
  bf16* geo_b = (bf16*)alloc((size_t)Nrows * 576 * 2);
  bf16* big_s = (bf16*)alloc((size_t)Ns * 576 * 2);
  bf16* big_t = (bf16*)alloc((size_t)Nt * 576 * 2);
  bf16* zpre  = (bf16*)alloc((size_t)Ns * 512 * 2);

  // ---- prep ----
  PrepP P;
  {
    const float* srcs[6] = {Wi1, Wi2, Wc1, Wc2, Ws1, Ws2};
    bf16* dsts[6]        = {Wi1b, Wi2b, Wc1b, Wc2b, Ws1sb, Ws2b};
    int slds[6] = {528, 528, 528, 528, 2576, 512};
    int rows[6] = {528, 1024, 528, 1024, 512, 256};
    int Ks[6]   = {528, 528, 528, 528, 528, 512};
    int Kps[6]  = {576, 576, 576, 576, 576, 512};
    int nblk = 0;
    for (int i = 0; i < 6; ++i) {
      P.Wsrc[i] = srcs[i]; P.Wdst[i] = dsts[i]; P.sld[i] = slds[i];
      P.rows[i] = rows[i]; P.K[i] = Ks[i]; P.Kpad[i] = Kps[i];
      P.off[i] = nblk;
      nblk += (rows[i] * Kps[i] + 255) / 256;
    }
    P.off[6] = nblk;
    P.zbuf = iacc; P.ztotal = 8192 + 8192 + Ns;
    nblk += (P.ztotal + 255) / 256;
    P.off[7] = nblk;
    P.geo = geo; P.geo_b = geo_b; P.Nrows = Nrows;
    nblk += ((Nrows * 72) + 255) / 256;
    P.off[8] = nblk;
    P.sics = sics; P.tics = tics; P.Ns = Ns; P.Nt = Nt; P.cnt = cnt;
    int n = Ns > Nt ? Ns : Nt;
    nblk += (n + 255) / 256;
    P.off[9] = nblk;
    prep_kernel<<<dim3(nblk), dim3(256), 0, stream>>>(P);
  }

  // ---- kernel A: L1-src, L1-tgt, z_pre ----
  kernelA<<<dim3(Ms * 5 + Mt * 5 + Ms * 4), dim3(256), 0, stream>>>(
      geo_b, Wi1b, Wc1b, Ws1sb, bi1, bc1, big_s, big_t, zpre, Ms, Mt);

  // ---- kernel B: L2-src, L2-tgt (batch sums, 128x256 blocks) + output fills ----
  float inv = 1.0f / sqrtf(528.0f);
  kernelB<<<dim3(Ms * 4 + Mt * 4 + 16384), dim3(256), 0, stream>>>(
      big_s, big_t, Wi2b, Wc2b, bi2, bc2, iacc, cacc, sics, tics, Ms, Mt,
      geo, pcd, cnt, out0, out1, out2, out3, Ns, inv);

  glob_kernel<<<dim3(1024), dim3(256), 0, stream>>>(iacc, cacc, cnt, Ws1, bs1, globb);
  s_empty_kernel<<<dim3(8), dim3(256), 0, stream>>>(globb, Ws2, bs2, Ws3, bs3, semp);
  zfix_kernel<<<dim3((Ns * 64 + 255) / 256), dim3(256), 0, stream>>>(zpre, globb, sics, Ns * 64);
  kernelC<<<dim3(Ms, 2), dim3(256), 0, stream>>>(zpre, Ws2b, bs2, Ws3, sbuf);
  scale_kernel<<<dim3(128), dim3(256), 0, stream>>>(sbuf, semp, cnt, bs3, out4);
}

// Round 7
// 538.200 us; speedup vs baseline: 1.0790x; 1.0790x over previous
//
#include <hip/hip_runtime.h>
#include <hip/hip_bf16.h>
#include <cstdint>
#include <cstddef>

typedef float f32x4 __attribute__((ext_vector_type(4)));
typedef __bf16 bf16x8v __attribute__((ext_vector_type(8)));
typedef __hip_bfloat16 bf16;

// async global->LDS, 16 B per lane (lds ptr: wave-uniform base + lane*16)
__device__ __forceinline__ void gld16(const void* g, void* l) {
  __builtin_amdgcn_global_load_lds((const __attribute__((address_space(1))) void*)g,
                                   (__attribute__((address_space(3))) void*)l, 16, 0, 0);
}

// bijective XCD-aware swizzle (m204 form): contiguous logical chunks per XCD
// [counter-verified: kernelB FETCH 271->84 MB, dur 130->120 us (R3 vs R0/R5)]
__device__ __forceinline__ int xcd_swz(int orig, int nwg) {
  int q = nwg >> 3, r = nwg & 7;
  int x = orig & 7, i = orig >> 3;
  return (x < r ? x * (q + 1) : r * (q + 1) + (x - r) * q) + i;
}

// ---------------- prep: weights->bf16(Kpad), zero accs, geo->bf16(ld576), maps ----------
// cnt layout: cnt[0..8] = src batch start offsets (cnt[8]=Ns), cnt[9..17] = tgt starts

struct PrepP {
  const float* Wsrc[6];
  bf16* Wdst[6];
  int sld[6], rows[6], K[6], Kpad[6];
  int off[10];            // jobs 0..5 weights, 6 zero, 7 geo_b (4-row ILP), 8 maps; off[9]=end
  float* zbuf; int ztotal;
  const float* geo; bf16* geo_b; int Nrows; int Q;   // Q = rows per ILP slice
  const int* sics; const int* tics; int Ns, Nt; int* cnt;
};

__global__ void prep_kernel(PrepP P) {
  int blk = blockIdx.x;
  int job = 0;
  while (job < 8 && blk >= P.off[job + 1]) ++job;
  int local = blk - P.off[job];
  if (job < 6) {
    int i = local * 256 + threadIdx.x;
    int kp = P.Kpad[job];
    int total = P.rows[job] * kp;
    if (i < total) {
      int r = i / kp, k = i - r * kp;
      float v = (k < P.K[job]) ? P.Wsrc[job][(size_t)r * P.sld[job] + k] : 0.f;
      P.Wdst[job][i] = __float2bfloat16(v);
    }
  } else if (job == 6) {
    int i = local * 256 + threadIdx.x;
    if (i < P.ztotal) P.zbuf[i] = 0.f;
  } else if (job == 7) {
    // geo -> geo_b (bf16, K-padded to 576); 4 rows per thread (strided Q) for load ILP
    int t = local * 256 + threadIdx.x;
    int r0 = t / 72, c8 = t - r0 * 72;
    if (r0 < P.Q) {
      int col = c8 * 8;
#pragma unroll
      for (int s = 0; s < 4; ++s) {
        int row = r0 + s * P.Q;
        if (row < P.Nrows) {
          bf16* dst = P.geo_b + (size_t)row * 576 + col;
          if (c8 < 66) {
            const float* sp = P.geo + (size_t)row * 528 + col;
            float4 f0 = ((const float4*)sp)[0], f1 = ((const float4*)sp)[1];
            bf16 h[8] = {__float2bfloat16(f0.x), __float2bfloat16(f0.y),
                         __float2bfloat16(f0.z), __float2bfloat16(f0.w),
                         __float2bfloat16(f1.x), __float2bfloat16(f1.y),
                         __float2bfloat16(f1.z), __float2bfloat16(f1.w)};
            ((uint4*)dst)[0] = *(uint4*)h;
          } else {
            uint4 z = {0u, 0u, 0u, 0u};
            ((uint4*)dst)[0] = z;      // K-pad cols 528..575
          }
        }
      }
    }
  } else {  // maps: batch start offsets, atomic-free
    int j = local * 256 + threadIdx.x;
    if (j < P.Ns) {
      if (j == 0) { P.cnt[0] = 0; P.cnt[8] = P.Ns; }
      else { int b = P.sics[j] >> 12; if ((P.sics[j - 1] >> 12) != b) P.cnt[b] = j; }
    }
    if (j < P.Nt) {
      if (j == 0) { P.cnt[9] = 0; P.cnt[17] = P.Nt; }
      else { int b = P.tics[j] >> 12; if ((P.tics[j - 1] >> 12) != b) P.cnt[9 + b] = j; }
    }
  }
}

// ---------------- GEMM core: 128x128 tile, BK=64 via twin 128x32 LDS buffers ----------------
// 8 outstanding global_load_lds, 32 MFMA per barrier pair.
__device__ __forceinline__ void gemm_core(
    const bf16* __restrict__ Aptr, int lda,
    const bf16* __restrict__ Bw, int ldb,
    int m0, int n0, int kiters,
    bf16* __restrict__ lA, bf16* __restrict__ lB,
    f32x4 acc[4][4])
{
  const int tid  = threadIdx.x;
  const int lane = tid & 63;
  const int quad = lane >> 4;
  const int l16  = lane & 15;
  const int wr   = tid >> 7;
  const int wc   = (tid >> 6) & 1;
  const int srow = tid >> 2;
  const int scol = (tid & 3) << 3;
  const bf16* aA0 = Aptr + (size_t)(m0 + srow) * lda + scol;
  const bf16* aA1 = aA0 + (size_t)64 * lda;
  const bf16* aB0 = Bw + (size_t)(n0 + srow) * ldb + scol;
  const bf16* aB1 = aB0 + (size_t)64 * ldb;
  bf16* lA00 = lA + tid * 8;        bf16* lA01 = lA + 2048 + tid * 8;
  bf16* lA10 = lA + 4096 + tid * 8; bf16* lA11 = lA + 6144 + tid * 8;
  bf16* lB00 = lB + tid * 8;        bf16* lB01 = lB + 2048 + tid * 8;
  bf16* lB10 = lB + 4096 + tid * 8; bf16* lB11 = lB + 6144 + tid * 8;

  for (int k = 0; k < kiters; ++k) {
    const int k0 = k * 64;
    gld16(aA0 + k0, lA00);      gld16(aA1 + k0, lA01);
    gld16(aA0 + k0 + 32, lA10); gld16(aA1 + k0 + 32, lA11);
    gld16(aB0 + k0, lB00);      gld16(aB1 + k0, lB01);
    gld16(aB0 + k0 + 32, lB10); gld16(aB1 + k0 + 32, lB11);
    __syncthreads();
#pragma unroll
    for (int kk = 0; kk < 2; ++kk) {
      bf16x8v af[4], bfr[4];
#pragma unroll
      for (int i = 0; i < 4; ++i) {
        af[i]  = *(const bf16x8v*)&lA[kk * 4096 + (wr * 64 + i * 16 + l16) * 32 + quad * 8];
        bfr[i] = *(const bf16x8v*)&lB[kk * 4096 + (wc * 64 + i * 16 + l16) * 32 + quad * 8];
      }
#pragma unroll
      for (int mi = 0; mi < 4; ++mi)
#pragma unroll
        for (int ni = 0; ni < 4; ++ni)
          acc[mi][ni] = __builtin_amdgcn_mfma_f32_16x16x32_bf16(af[mi], bfr[ni], acc[mi][ni], 0, 0, 0);
    }
    __syncthreads();
  }
}

// ---------------- kernel A: GEMM1 (src L1) + GEMM3 (tgt L1) + GEMM5-pre (z w/o glob) ------
__global__ __launch_bounds__(256, 2)
void kernelA(const bf16* __restrict__ geo_b,
             const bf16* __restrict__ Wi1b, const bf16* __restrict__ Wc1b,
             const bf16* __restrict__ Ws1sb,
             const float* __restrict__ bi1, const float* __restrict__ bc1,
             bf16* __restrict__ big_s, bf16* __restrict__ big_t,
             bf16* __restrict__ zpre, int Ms, int Mt)
{
  __shared__ alignas(16) bf16 lA[8192], lB[8192];
  const int x = xcd_swz(blockIdx.x, gridDim.x);
  const int e0 = Ms * 5, e1 = e0 + Mt * 5;
  const bf16 *A, *B; const float* bias = nullptr; bf16* out;
  int m0, n0, ldo, epi;
  if (x < e0) {
    int mt = x / 5, nt = x - mt * 5;
    m0 = mt * 128; n0 = nt * 128;
    A = geo_b; B = Wi1b; bias = bi1; out = big_s; ldo = 576; epi = 0;
  } else if (x < e1) {
    int y = x - e0; int mt = y / 5, nt = y - mt * 5;
    m0 = mt * 128; n0 = nt * 128;
    A = geo_b + (size_t)Ms * 128 * 576; B = Wc1b; bias = bc1; out = big_t; ldo = 576; epi = 0;
  } else {
    int y = x - e1; int mt = y / 4, nt = y - mt * 4;
    m0 = mt * 128; n0 = nt * 128;
    A = geo_b; B = Ws1sb; out = zpre; ldo = 512; epi = 1;
  }

  f32x4 acc[4][4];
  const f32x4 z4 = {0.f, 0.f, 0.f, 0.f};
#pragma unroll
  for (int i = 0; i < 4; ++i)
#pragma unroll
    for (int j = 0; j < 4; ++j) acc[i][j] = z4;

  gemm_core(A, 576, B, 576, m0, n0, 9, lA, lB, acc);

  const int lane = threadIdx.x & 63, quad = lane >> 4, l16 = lane & 15;
  const int wr = threadIdx.x >> 7, wc = (threadIdx.x >> 6) & 1;
#pragma unroll
  for (int mi = 0; mi < 4; ++mi) {
#pragma unroll
    for (int r = 0; r < 4; ++r) {
      const int row = m0 + wr * 64 + mi * 16 + quad * 4 + r;
#pragma unroll
      for (int ni = 0; ni < 4; ++ni) {
        const int col = n0 + wc * 64 + ni * 16 + l16;
        if (epi == 0) {
          if (col < 528)
            out[(size_t)row * ldo + col] = __float2bfloat16(fmaxf(acc[mi][ni][r] + bias[col], 0.f));
          else if (col < 576)
            out[(size_t)row * ldo + col] = __float2bfloat16(0.f);
        } else {
          out[(size_t)row * ldo + col] = __float2bfloat16(acc[mi][ni][r]);  // z_pre, raw
        }
      }
    }
  }
}

// ---------------- kernel B: GEMM2 + GEMM4 (batch-sum epilogue) + output fills (tail) -------
__global__ __launch_bounds__(256, 2)
void kernelB(const bf16* __restrict__ big_s, const bf16* __restrict__ big_t,
             const bf16* __restrict__ Wi2b, const bf16* __restrict__ Wc2b,
             const float* __restrict__ bi2, const float* __restrict__ bc2,
             float* __restrict__ iacc, float* __restrict__ cacc,
             const int* __restrict__ sics, const int* __restrict__ tics,
             int Ms, int Mt,
             const float* __restrict__ geo, const float* __restrict__ pcd,
             const int* __restrict__ cnt,
             float* __restrict__ out0, float* __restrict__ out1,
             float* __restrict__ out2, float* __restrict__ out3,
             int Ns, float inv)
{
  __shared__ alignas(16) bf16 lA[8192], lB[8192];
  const int xb = blockIdx.x;
  const int e0 = Ms * 8, e1 = e0 + Mt * 8;
  if (xb >= e1) {
    // -------- fill job: 4 output rows per block, 64 lanes/row --------
    int f = xb - e1;
    int lane = threadIdx.x & 63;
    int rv = f * 4 + (threadIdx.x >> 6);       // 0..65535
    bool is_t = rv >= 32768;
    int pos = is_t ? rv - 32768 : rv;
    int b = pos >> 12, r = pos & 4095;
    int base = is_t ? cnt[9 + b] : cnt[b];
    int lim  = (is_t ? cnt[9 + b + 1] : cnt[b + 1]) - base;
    float* op = (is_t ? out1 : out0) + (size_t)pos * 528;
    float* pp = (is_t ? out3 : out2) + (size_t)pos * 3;
    if (r < lim) {
      int sr = (is_t ? Ns : 0) + base + r;
      const float4* g = (const float4*)(geo + (size_t)sr * 528);
      for (int d = lane; d < 132; d += 64) {
        float4 v = g[d];
        float4 s = {v.x * inv, v.y * inv, v.z * inv, v.w * inv};
        ((float4*)op)[d] = s;
      }
      if (lane < 3) pp[lane] = pcd[(size_t)sr * 3 + lane];
    } else {
      float4 z = {0.f, 0.f, 0.f, 0.f};
      for (int d = lane; d < 132; d += 64) ((float4*)op)[d] = z;
      if (lane < 3) pp[lane] = 0.f;
    }
    return;
  }
  // -------- GEMM job --------
  const int x = xcd_swz(xb, e1);
  const bf16 *A, *B; const float* bias; float* red; const int* ridx;
  int m0, n0;
  if (x < e0) {
    int mt = x / 8, nt = x - mt * 8;
    m0 = mt * 128; n0 = nt * 128;
    A = big_s; B = Wi2b; bias = bi2; red = iacc; ridx = sics;
  } else {
    int y = x - e0; int mt = y / 8, nt = y - mt * 8;
    m0 = mt * 128; n0 = nt * 128;
    A = big_t; B = Wc2b; bias = bc2; red = cacc; ridx = tics;
  }

  f32x4 acc[4][4];
  const f32x4 z4 = {0.f, 0.f, 0.f, 0.f};
#pragma unroll
  for (int i = 0; i < 4; ++i)
#pragma unroll
    for (int j = 0; j < 4; ++j) acc[i][j] = z4;

  gemm_core(A, 576, B, 576, m0, n0, 9, lA, lB, acc);

  // per-batch column sums (rows batch-sorted; 128-row tile spans <=2 batches)
  const int lane = threadIdx.x & 63, quad = lane >> 4, l16 = lane & 15;
  const int wr = threadIdx.x >> 7, wc = (threadIdx.x >> 6) & 1;
  const int b0r = ridx[m0] >> 12;
#pragma unroll
  for (int ni = 0; ni < 4; ++ni) {
    const int col = n0 + wc * 64 + ni * 16 + l16;
    const float bcol = bias[col];
#pragma unroll
    for (int mi = 0; mi < 4; ++mi) {
      float v0 = 0.f, v1 = 0.f;
#pragma unroll
      for (int r = 0; r < 4; ++r) {
        const int row = m0 + wr * 64 + mi * 16 + quad * 4 + r;
        const float v = fmaxf(acc[mi][ni][r] + bcol, 0.f);
        const int b = ridx[row] >> 12;
        if (b == b0r) v0 += v; else v1 += v;
      }
      v0 += __shfl_xor(v0, 16, 64); v0 += __shfl_xor(v0, 32, 64);
      v1 += __shfl_xor(v1, 16, 64); v1 += __shfl_xor(v1, 32, 64);
      if (quad == 0) {
        atomicAdd(&red[b0r * 1024 + col], v0);
        if (b0r + 1 < 8 && v1 != 0.f) atomicAdd(&red[(b0r + 1) * 1024 + col], v1);
      }
    }
  }
}

// ---------------- kernel C: GEMM6 + fused zfix (A = relu(zpre+glob)) + fused s-dot ---------
__global__ __launch_bounds__(256, 2)
void kernelC(const bf16* __restrict__ zpre, const bf16* __restrict__ Ws2b,
             const float* __restrict__ bs2, const float* __restrict__ Ws3,
             const float* __restrict__ globv, const int* __restrict__ sics,
             float* __restrict__ sbuf)
{
  __shared__ alignas(16) bf16 lA[8192], lB[8192];
  const int x = xcd_swz(blockIdx.x, gridDim.x);
  const int m0 = (x >> 1) * 128, n0 = (x & 1) * 128;
  const int tid  = threadIdx.x;
  const int lane = tid & 63, quad = lane >> 4, l16 = lane & 15;
  const int wr = tid >> 7, wc = (tid >> 6) & 1;
  const int srow = tid >> 2;
  const int scol = (tid & 3) << 3;

  // A-staging with fused zfix: z = relu(zpre + glob[b(row)])  (bit-identical to old zfix path)
  const int r0g = m0 + srow, r1g = r0g + 64;
  const float* gv0 = globv + ((size_t)(sics[r0g] >> 12) << 9);
  const float* gv1 = globv + ((size_t)(sics[r1g] >> 12) << 9);
  const bf16* za0 = zpre + (size_t)r0g * 512 + scol;
  const bf16* za1 = zpre + (size_t)r1g * 512 + scol;
  // B-staging via global_load_lds
  const bf16* aB0 = Ws2b + (size_t)(n0 + srow) * 512 + scol;
  const bf16* aB1 = aB0 + (size_t)64 * 512;
  bf16* lB00 = lB + tid * 8;        bf16* lB01 = lB + 2048 + tid * 8;
  bf16* lB10 = lB + 4096 + tid * 8; bf16* lB11 = lB + 6144 + tid * 8;

  f32x4 acc[4][4];
  const f32x4 z4 = {0.f, 0.f, 0.f, 0.f};
#pragma unroll
  for (int i = 0; i < 4; ++i)
#pragma unroll
    for (int j = 0; j < 4; ++j) acc[i][j] = z4;

  auto stageA = [&](const bf16* src, const float* gv, int col, bf16* dst) {
    uint4 u = *(const uint4*)src;
    bf16 e[8]; *(uint4*)e = u;
    bf16 o[8];
#pragma unroll
    for (int i = 0; i < 8; ++i)
      o[i] = __float2bfloat16(fmaxf(__bfloat162float(e[i]) + gv[col + i], 0.f));
    *(uint4*)dst = *(uint4*)o;
  };

  for (int k = 0; k < 8; ++k) {
    const int k0 = k * 64;
    gld16(aB0 + k0, lB00);      gld16(aB1 + k0, lB01);
    gld16(aB0 + k0 + 32, lB10); gld16(aB1 + k0 + 32, lB11);
    stageA(za0 + k0,      gv0, k0 + scol,      lA + tid * 8);
    stageA(za1 + k0,      gv1, k0 + scol,      lA + 2048 + tid * 8);
    stageA(za0 + k0 + 32, gv0, k0 + scol + 32, lA + 4096 + tid * 8);
    stageA(za1 + k0 + 32, gv1, k0 + scol + 32, lA + 6144 + tid * 8);
    __syncthreads();
#pragma unroll
    for (int kk = 0; kk < 2; ++kk) {
      bf16x8v af[4], bfr[4];
#pragma unroll
      for (int i = 0; i < 4; ++i) {
        af[i]  = *(const bf16x8v*)&lA[kk * 4096 + (wr * 64 + i * 16 + l16) * 32 + quad * 8];
        bfr[i] = *(const bf16x8v*)&lB[kk * 4096 + (wc * 64 + i * 16 + l16) * 32 + quad * 8];
      }
#pragma unroll
      for (int mi = 0; mi < 4; ++mi)
#pragma unroll
        for (int ni = 0; ni < 4; ++ni)
          acc[mi][ni] = __builtin_amdgcn_mfma_f32_16x16x32_bf16(af[mi], bfr[ni], acc[mi][ni], 0, 0, 0);
    }
    __syncthreads();
  }

#pragma unroll
  for (int mi = 0; mi < 4; ++mi) {
#pragma unroll
    for (int r = 0; r < 4; ++r) {
      const int row = m0 + wr * 64 + mi * 16 + quad * 4 + r;
      float p = 0.f;
#pragma unroll
      for (int ni = 0; ni < 4; ++ni) {
        const int col = n0 + wc * 64 + ni * 16 + l16;
        p += fmaxf(acc[mi][ni][r] + bs2[col], 0.f) * Ws3[col];
      }
      p += __shfl_xor(p, 1, 64); p += __shfl_xor(p, 2, 64);
      p += __shfl_xor(p, 4, 64); p += __shfl_xor(p, 8, 64);
      if (l16 == 0) atomicAdd(&sbuf[row], p);
    }
  }
}

// glob[b][o] = bs1[o] + (iacc[b]/ns) . Ws1[o,528:1552] + (cacc[b]/nt) . Ws1[o,1552:2576]
__global__ __launch_bounds__(256) void glob_kernel(const float* __restrict__ iacc,
                                                   const float* __restrict__ cacc,
                                                   const int* __restrict__ cnt,
                                                   const float* __restrict__ Ws1,
                                                   const float* __restrict__ bs1,
                                                   float* __restrict__ globv) {
  int w    = (blockIdx.x * 256 + threadIdx.x) >> 6;  // 4096 waves
  int lane = threadIdx.x & 63;
  int b = w >> 9;
  int o = w & 511;
  const float* wi  = Ws1 + (size_t)o * 2576 + 528;
  const float* wcp = Ws1 + (size_t)o * 2576 + 1552;
  float a1 = 0.f, a2 = 0.f;
  for (int k = lane; k < 1024; k += 64) {
    a1 += iacc[b * 1024 + k] * wi[k];
    a2 += cacc[b * 1024 + k] * wcp[k];
  }
  for (int off = 32; off; off >>= 1) {
    a1 += __shfl_xor(a1, off, 64);
    a2 += __shfl_xor(a2, off, 64);
  }
  if (lane == 0) {
    float ns = (float)(cnt[b + 1] - cnt[b]);
    float nt = (float)(cnt[9 + b + 1] - cnt[9 + b]);
    globv[b * 512 + o] = bs1[o] + a1 / ns + a2 / nt;
  }
}

// s value for an all-zero (invalid) row of batch b — wave-parallel, coalesced Ws2 reads.
// wave w handles t in [w*64, w*64+64); lanes split the o-sum (coalesced 256B reads).
__global__ __launch_bounds__(256) void s_empty_kernel(const float* __restrict__ globv,
                                                      const float* __restrict__ Ws2,
                                                      const float* __restrict__ bs2,
                                                      const float* __restrict__ Ws3,
                                                      const float* __restrict__ bs3,
                                                      float* __restrict__ semp) {
  __shared__ float zrow[512];
  __shared__ float wsum[4];
  int b = blockIdx.x, t = threadIdx.x;
  zrow[t]       = fmaxf(globv[b * 512 + t], 0.f);
  zrow[t + 256] = fmaxf(globv[b * 512 + t + 256], 0.f);
  __syncthreads();
  int w = t >> 6, lane = t & 63;
  float ws = 0.f;
  for (int tt = w * 64; tt < w * 64 + 64; ++tt) {
    float a = 0.f;
#pragma unroll
    for (int oi = 0; oi < 8; ++oi) {
      int o = lane + oi * 64;
      a += zrow[o] * Ws2[(size_t)tt * 512 + o];
    }
    for (int off = 32; off; off >>= 1) a += __shfl_xor(a, off, 64);
    if (lane == 0) ws += fmaxf(a + bs2[tt], 0.f) * Ws3[tt];
  }
  if (lane == 0) wsum[w] = ws;
  __syncthreads();
  if (t == 0) semp[b] = wsum[0] + wsum[1] + wsum[2] + wsum[3] + bs3[0];
}

__global__ void scale_kernel(const float* __restrict__ sbuf,
                             const float* __restrict__ semp,
                             const int* __restrict__ cnt,
                             const float* __restrict__ bs3,
                             float* __restrict__ out4) {
  int i = blockIdx.x * 256 + threadIdx.x;   // 0..32767
  if (i >= 32768) return;
  int b = i >> 12, r = i & 4095;
  int base = cnt[b];
  int lim = cnt[b + 1] - base;
  float s = (r < lim) ? sbuf[base + r] + bs3[0] : semp[b];
  out4[i] = 1.f / (1.f + expf(-s)) - 0.5f;
}

// ---------------- host ----------------

extern "C" void kernel_launch(void* const* d_in, const int* in_sizes, int n_in,
                              void* d_out, int out_size, void* d_ws, size_t ws_size,
                              hipStream_t stream) {
  const float* geo = (const float*)d_in[0];
  const float* pcd = (const float*)d_in[1];
  const float* Wi1 = (const float*)d_in[2];
  const float* bi1 = (const float*)d_in[3];
  const float* Wi2 = (const float*)d_in[4];
  const float* bi2 = (const float*)d_in[5];
  const float* Wc1 = (const float*)d_in[6];
  const float* bc1 = (const float*)d_in[7];
  const float* Wc2 = (const float*)d_in[8];
  const float* bc2 = (const float*)d_in[9];
  const float* Ws1 = (const float*)d_in[10];
  const float* bs1 = (const float*)d_in[11];
  const float* Ws2 = (const float*)d_in[12];
  const float* bs2 = (const float*)d_in[13];
  const float* Ws3 = (const float*)d_in[14];
  const float* bs3 = (const float*)d_in[15];
  const int* sics = (const int*)d_in[18];
  const int* tics = (const int*)d_in[19];
  const int Ns = in_sizes[18];   // 23552 = 184*128
  const int Nt = in_sizes[19];   // 24704 = 193*128
  const int Ms = Ns / 128, Mt = Nt / 128;
  const int Nrows = Ns + Nt;

  float* out0 = (float*)d_out;                      // (8,4096,528)
  float* out1 = out0 + (size_t)8 * 4096 * 528;      // (8,4096,528)
  float* out2 = out1 + (size_t)8 * 4096 * 528;      // (8,4096,3)
  float* out3 = out2 + (size_t)8 * 4096 * 3;        // (8,4096,3)
  float* out4 = out3 + (size_t)8 * 4096 * 3;        // (8,1,4096)

  char* wp = (char*)d_ws;
  auto alloc = [&](size_t bytes) -> void* {
    void* p = (void*)wp;
    wp += (bytes + 255) & ~(size_t)255;
    return p;
  };
  int*   cnt   = (int*)  alloc(128);
  float* iacc  = (float*)alloc((size_t)8 * 1024 * 4);   // iacc/cacc/sbuf contiguous (zero job)
  float* cacc  = (float*)alloc((size_t)8 * 1024 * 4);
  float* sbuf  = (float*)alloc((size_t)Ns * 4);
  float* globb = (float*)alloc((size_t)8 * 512 * 4);
  float* semp  = (float*)alloc(64);
  bf16* Wi1b  = (bf16*)alloc((size_t)640  * 576 * 2);   // rows 528..639 uninit (cols discarded)
  bf16* Wi2b  = (bf16*)alloc((size_t)1024 * 576 * 2);
  bf16* Wc1b  = (bf16*)alloc((size_t)640  * 576 * 2);
  bf16* Wc2b  = (bf16*)alloc((size_t)1024 * 576 * 2);
  bf16* Ws1sb = (bf16*)alloc((size_t)512  * 576 * 2);
  bf16* Ws2b  = (bf16*)alloc((size_t)256  * 512 * 2);
  bf16* geo_b = (bf16*)alloc((size_t)Nrows * 576 * 2);
  bf16* big_s = (bf16*)alloc((size_t)Ns * 576 * 2);
  bf16* big_t = (bf16*)alloc((size_t)Nt * 576 * 2);
  bf16* zpre  = (bf16*)alloc((size_t)Ns * 512 * 2);

  float inv = 1.0f / sqrtf(528.0f);

  // ---- prep: weights + zero accs + geo_b conversion (4-row ILP) + maps ----
  PrepP P;
  {
    const float* srcs[6] = {Wi1, Wi2, Wc1, Wc2, Ws1, Ws2};
    bf16* dsts[6]        = {Wi1b, Wi2b, Wc1b, Wc2b, Ws1sb, Ws2b};
    int slds[6] = {528, 528, 528, 528, 2576, 512};
    int rows[6] = {528, 1024, 528, 1024, 512, 256};
    int Ks[6]   = {528, 528, 528, 528, 528, 512};
    int Kps[6]  = {576, 576, 576, 576, 576, 512};
    int nblk = 0;
    for (int i = 0; i < 6; ++i) {
      P.Wsrc[i] = srcs[i]; P.Wdst[i] = dsts[i]; P.sld[i] = slds[i];
      P.rows[i] = rows[i]; P.K[i] = Ks[i]; P.Kpad[i] = Kps[i];
      P.off[i] = nblk;
      nblk += (rows[i] * Kps[i] + 255) / 256;
    }
    P.off[6] = nblk;
    P.zbuf = iacc; P.ztotal = 8192 + 8192 + Ns;
    nblk += (P.ztotal + 255) / 256;
    P.off[7] = nblk;
    P.geo = geo; P.geo_b = geo_b; P.Nrows = Nrows;
    P.Q = (Nrows + 3) >> 2;
    nblk += (P.Q * 72 + 255) / 256;
    P.off[8] = nblk;
    P.sics = sics; P.tics = tics; P.Ns = Ns; P.Nt = Nt; P.cnt = cnt;
    int n = Ns > Nt ? Ns : Nt;
    nblk += (n + 255) / 256;
    P.off[9] = nblk;
    prep_kernel<<<dim3(nblk), dim3(256), 0, stream>>>(P);
  }

  // ---- kernel A: L1-src, L1-tgt, z_pre (XCD-swizzled) ----
  kernelA<<<dim3(Ms * 5 + Mt * 5 + Ms * 4), dim3(256), 0, stream>>>(
      geo_b, Wi1b, Wc1b, Ws1sb, bi1, bc1, big_s, big_t, zpre, Ms, Mt);

  // ---- kernel B: L2-src, L2-tgt (batch sums, XCD-swizzled) + output fills at tail ----
  kernelB<<<dim3(Ms * 8 + Mt * 8 + 16384), dim3(256), 0, stream>>>(
      big_s, big_t, Wi2b, Wc2b, bi2, bc2, iacc, cacc, sics, tics, Ms, Mt,
      geo, pcd, cnt, out0, out1, out2, out3, Ns, inv);

  glob_kernel<<<dim3(1024), dim3(256), 0, stream>>>(iacc, cacc, cnt, Ws1, bs1, globb);
  s_empty_kernel<<<dim3(8), dim3(256), 0, stream>>>(globb, Ws2, bs2, Ws3, bs3, semp);
  kernelC<<<dim3(Ms * 2), dim3(256), 0, stream>>>(zpre, Ws2b, bs2, Ws3, globb, sics, sbuf);
  scale_kernel<<<dim3(128), dim3(256), 0, stream>>>(sbuf, semp, cnt, bs3, out4);
}

// Round 8
// 508.139 us; speedup vs baseline: 1.1429x; 1.0592x over previous
//
#include <hip/hip_runtime.h>
#include <hip/hip_bf16.h>
#include <cstdint>
#include <cstddef>

typedef float f32x4 __attribute__((ext_vector_type(4)));
typedef __bf16 bf16x8v __attribute__((ext_vector_type(8)));
typedef __hip_bfloat16 bf16;

// async global->LDS, 16 B per lane (lds ptr: wave-uniform base + lane*16)
__device__ __forceinline__ void gld16(const void* g, void* l) {
  __builtin_amdgcn_global_load_lds((const __attribute__((address_space(1))) void*)g,
                                   (__attribute__((address_space(3))) void*)l, 16, 0, 0);
}

// bijective XCD-aware swizzle (m204 form): contiguous logical chunks per XCD
// [counter-verified: kernelB FETCH 271->84 MB, dur 130->122 us (R3/R7 vs R0/R5)]
__device__ __forceinline__ int xcd_swz(int orig, int nwg) {
  int q = nwg >> 3, r = nwg & 7;
  int x = orig & 7, i = orig >> 3;
  return (x < r ? x * (q + 1) : r * (q + 1) + (x - r) * q) + i;
}

// ---------------- prep: weights->bf16(Kpad), zero accs, geo->bf16(ld576), maps ----------
// cnt layout: cnt[0..8] = src batch start offsets (cnt[8]=Ns), cnt[9..17] = tgt starts

struct PrepP {
  const float* Wsrc[6];
  bf16* Wdst[6];
  int sld[6], rows[6], K[6], Kpad[6];
  int off[10];            // jobs 0..5 weights, 6 zero, 7 geo_b (4-row ILP), 8 maps; off[9]=end
  float* zbuf; int ztotal;
  const float* geo; bf16* geo_b; int Nrows; int Q;   // Q = rows per ILP slice
  const int* sics; const int* tics; int Ns, Nt; int* cnt;
};

__global__ void prep_kernel(PrepP P) {
  int blk = blockIdx.x;
  int job = 0;
  while (job < 8 && blk >= P.off[job + 1]) ++job;
  int local = blk - P.off[job];
  if (job < 6) {
    int i = local * 256 + threadIdx.x;
    int kp = P.Kpad[job];
    int total = P.rows[job] * kp;
    if (i < total) {
      int r = i / kp, k = i - r * kp;
      float v = (k < P.K[job]) ? P.Wsrc[job][(size_t)r * P.sld[job] + k] : 0.f;
      P.Wdst[job][i] = __float2bfloat16(v);
    }
  } else if (job == 6) {
    int i = local * 256 + threadIdx.x;
    if (i < P.ztotal) P.zbuf[i] = 0.f;
  } else if (job == 7) {
    // geo -> geo_b (bf16, K-padded to 576); 4 rows per thread (strided Q) for load ILP
    int t = local * 256 + threadIdx.x;
    int r0 = t / 72, c8 = t - r0 * 72;
    if (r0 < P.Q) {
      int col = c8 * 8;
#pragma unroll
      for (int s = 0; s < 4; ++s) {
        int row = r0 + s * P.Q;
        if (row < P.Nrows) {
          bf16* dst = P.geo_b + (size_t)row * 576 + col;
          if (c8 < 66) {
            const float* sp = P.geo + (size_t)row * 528 + col;
            float4 f0 = ((const float4*)sp)[0], f1 = ((const float4*)sp)[1];
            bf16 h[8] = {__float2bfloat16(f0.x), __float2bfloat16(f0.y),
                         __float2bfloat16(f0.z), __float2bfloat16(f0.w),
                         __float2bfloat16(f1.x), __float2bfloat16(f1.y),
                         __float2bfloat16(f1.z), __float2bfloat16(f1.w)};
            ((uint4*)dst)[0] = *(uint4*)h;
          } else {
            uint4 z = {0u, 0u, 0u, 0u};
            ((uint4*)dst)[0] = z;      // K-pad cols 528..575
          }
        }
      }
    }
  } else {  // maps: batch start offsets, atomic-free
    int j = local * 256 + threadIdx.x;
    if (j < P.Ns) {
      if (j == 0) { P.cnt[0] = 0; P.cnt[8] = P.Ns; }
      else { int b = P.sics[j] >> 12; if ((P.sics[j - 1] >> 12) != b) P.cnt[b] = j; }
    }
    if (j < P.Nt) {
      if (j == 0) { P.cnt[9] = 0; P.cnt[17] = P.Nt; }
      else { int b = P.tics[j] >> 12; if ((P.tics[j - 1] >> 12) != b) P.cnt[9 + b] = j; }
    }
  }
}

// ---------------- GEMM core: 128x128 tile, BK=64 via twin 128x32 LDS buffers ----------------
// 8 outstanding global_load_lds, 32 MFMA per barrier pair.
__device__ __forceinline__ void gemm_core(
    const bf16* __restrict__ Aptr, int lda,
    const bf16* __restrict__ Bw, int ldb,
    int m0, int n0, int kiters,
    bf16* __restrict__ lA, bf16* __restrict__ lB,
    f32x4 acc[4][4])
{
  const int tid  = threadIdx.x;
  const int lane = tid & 63;
  const int quad = lane >> 4;
  const int l16  = lane & 15;
  const int wr   = tid >> 7;
  const int wc   = (tid >> 6) & 1;
  const int srow = tid >> 2;
  const int scol = (tid & 3) << 3;
  const bf16* aA0 = Aptr + (size_t)(m0 + srow) * lda + scol;
  const bf16* aA1 = aA0 + (size_t)64 * lda;
  const bf16* aB0 = Bw + (size_t)(n0 + srow) * ldb + scol;
  const bf16* aB1 = aB0 + (size_t)64 * ldb;
  bf16* lA00 = lA + tid * 8;        bf16* lA01 = lA + 2048 + tid * 8;
  bf16* lA10 = lA + 4096 + tid * 8; bf16* lA11 = lA + 6144 + tid * 8;
  bf16* lB00 = lB + tid * 8;        bf16* lB01 = lB + 2048 + tid * 8;
  bf16* lB10 = lB + 4096 + tid * 8; bf16* lB11 = lB + 6144 + tid * 8;

  for (int k = 0; k < kiters; ++k) {
    const int k0 = k * 64;
    gld16(aA0 + k0, lA00);      gld16(aA1 + k0, lA01);
    gld16(aA0 + k0 + 32, lA10); gld16(aA1 + k0 + 32, lA11);
    gld16(aB0 + k0, lB00);      gld16(aB1 + k0, lB01);
    gld16(aB0 + k0 + 32, lB10); gld16(aB1 + k0 + 32, lB11);
    __syncthreads();
#pragma unroll
    for (int kk = 0; kk < 2; ++kk) {
      bf16x8v af[4], bfr[4];
#pragma unroll
      for (int i = 0; i < 4; ++i) {
        af[i]  = *(const bf16x8v*)&lA[kk * 4096 + (wr * 64 + i * 16 + l16) * 32 + quad * 8];
        bfr[i] = *(const bf16x8v*)&lB[kk * 4096 + (wc * 64 + i * 16 + l16) * 32 + quad * 8];
      }
#pragma unroll
      for (int mi = 0; mi < 4; ++mi)
#pragma unroll
        for (int ni = 0; ni < 4; ++ni)
          acc[mi][ni] = __builtin_amdgcn_mfma_f32_16x16x32_bf16(af[mi], bfr[ni], acc[mi][ni], 0, 0, 0);
    }
    __syncthreads();
  }
}

// ---------------- kernel A: GEMM1 (src L1) + GEMM5-pre (zpre) + GEMM3 (tgt L1) -------------
// Block mapping: each src row-panel's 9 col-tile blocks (5 L1 + 4 zpre) are logically
// contiguous so the XCD swizzle keeps them on one L2 -> A-panel fetched once, not twice.
__global__ __launch_bounds__(256, 2)
void kernelA(const bf16* __restrict__ geo_b,
             const bf16* __restrict__ Wi1b, const bf16* __restrict__ Wc1b,
             const bf16* __restrict__ Ws1sb,
             const float* __restrict__ bi1, const float* __restrict__ bc1,
             bf16* __restrict__ big_s, bf16* __restrict__ big_t,
             bf16* __restrict__ zpre, int Ms, int Mt)
{
  __shared__ alignas(16) bf16 lA[8192], lB[8192];
  const int x = xcd_swz(blockIdx.x, gridDim.x);
  const int e0 = Ms * 9;
  const bf16 *A, *B; const float* bias = bi1; bf16* out;
  int m0, n0, ldo, epi;
  if (x < e0) {
    int mt = x / 9, j = x - mt * 9;
    m0 = mt * 128;
    if (j < 5) {
      n0 = j * 128;
      A = geo_b; B = Wi1b; bias = bi1; out = big_s; ldo = 576; epi = 0;
    } else {
      n0 = (j - 5) * 128;
      A = geo_b; B = Ws1sb; out = zpre; ldo = 512; epi = 1;
    }
  } else {
    int y = x - e0; int mt = y / 5, nt = y - mt * 5;
    m0 = mt * 128; n0 = nt * 128;
    A = geo_b + (size_t)Ms * 128 * 576; B = Wc1b; bias = bc1; out = big_t; ldo = 576; epi = 0;
  }

  f32x4 acc[4][4];
  const f32x4 z4 = {0.f, 0.f, 0.f, 0.f};
#pragma unroll
  for (int i = 0; i < 4; ++i)
#pragma unroll
    for (int j = 0; j < 4; ++j) acc[i][j] = z4;

  gemm_core(A, 576, B, 576, m0, n0, 9, lA, lB, acc);

  const int lane = threadIdx.x & 63, quad = lane >> 4, l16 = lane & 15;
  const int wr = threadIdx.x >> 7, wc = (threadIdx.x >> 6) & 1;
#pragma unroll
  for (int mi = 0; mi < 4; ++mi) {
#pragma unroll
    for (int r = 0; r < 4; ++r) {
      const int row = m0 + wr * 64 + mi * 16 + quad * 4 + r;
#pragma unroll
      for (int ni = 0; ni < 4; ++ni) {
        const int col = n0 + wc * 64 + ni * 16 + l16;
        if (epi == 0) {
          if (col < 528)
            out[(size_t)row * ldo + col] = __float2bfloat16(fmaxf(acc[mi][ni][r] + bias[col], 0.f));
          else if (col < 576)
            out[(size_t)row * ldo + col] = __float2bfloat16(0.f);
        } else {
          out[(size_t)row * ldo + col] = __float2bfloat16(acc[mi][ni][r]);  // z_pre, raw
        }
      }
    }
  }
}

// ---------------- kernel B: GEMM2 + GEMM4 (batch-sum epilogue) + output fills (tail) -------
__global__ __launch_bounds__(256, 2)
void kernelB(const bf16* __restrict__ big_s, const bf16* __restrict__ big_t,
             const bf16* __restrict__ Wi2b, const bf16* __restrict__ Wc2b,
             const float* __restrict__ bi2, const float* __restrict__ bc2,
             float* __restrict__ iacc, float* __restrict__ cacc,
             const int* __restrict__ sics, const int* __restrict__ tics,
             int Ms, int Mt,
             const float* __restrict__ geo, const float* __restrict__ pcd,
             const int* __restrict__ cnt,
             float* __restrict__ out0, float* __restrict__ out1,
             float* __restrict__ out2, float* __restrict__ out3,
             int Ns, float inv)
{
  __shared__ alignas(16) bf16 lA[8192], lB[8192];
  const int xb = blockIdx.x;
  const int e0 = Ms * 8, e1 = e0 + Mt * 8;
  if (xb >= e1) {
    // -------- fill job: 4 output rows per block, 64 lanes/row --------
    int f = xb - e1;
    int lane = threadIdx.x & 63;
    int rv = f * 4 + (threadIdx.x >> 6);       // 0..65535
    bool is_t = rv >= 32768;
    int pos = is_t ? rv - 32768 : rv;
    int b = pos >> 12, r = pos & 4095;
    int base = is_t ? cnt[9 + b] : cnt[b];
    int lim  = (is_t ? cnt[9 + b + 1] : cnt[b + 1]) - base;
    float* op = (is_t ? out1 : out0) + (size_t)pos * 528;
    float* pp = (is_t ? out3 : out2) + (size_t)pos * 3;
    if (r < lim) {
      int sr = (is_t ? Ns : 0) + base + r;
      const float4* g = (const float4*)(geo + (size_t)sr * 528);
      for (int d = lane; d < 132; d += 64) {
        float4 v = g[d];
        float4 s = {v.x * inv, v.y * inv, v.z * inv, v.w * inv};
        ((float4*)op)[d] = s;
      }
      if (lane < 3) pp[lane] = pcd[(size_t)sr * 3 + lane];
    } else {
      float4 z = {0.f, 0.f, 0.f, 0.f};
      for (int d = lane; d < 132; d += 64) ((float4*)op)[d] = z;
      if (lane < 3) pp[lane] = 0.f;
    }
    return;
  }
  // -------- GEMM job --------
  const int x = xcd_swz(xb, e1);
  const bf16 *A, *B; const float* bias; float* red; const int* ridx;
  int m0, n0;
  if (x < e0) {
    int mt = x / 8, nt = x - mt * 8;
    m0 = mt * 128; n0 = nt * 128;
    A = big_s; B = Wi2b; bias = bi2; red = iacc; ridx = sics;
  } else {
    int y = x - e0; int mt = y / 8, nt = y - mt * 8;
    m0 = mt * 128; n0 = nt * 128;
    A = big_t; B = Wc2b; bias = bc2; red = cacc; ridx = tics;
  }

  f32x4 acc[4][4];
  const f32x4 z4 = {0.f, 0.f, 0.f, 0.f};
#pragma unroll
  for (int i = 0; i < 4; ++i)
#pragma unroll
    for (int j = 0; j < 4; ++j) acc[i][j] = z4;

  gemm_core(A, 576, B, 576, m0, n0, 9, lA, lB, acc);

  // per-batch column sums (rows batch-sorted; 128-row tile spans <=2 batches)
  const int lane = threadIdx.x & 63, quad = lane >> 4, l16 = lane & 15;
  const int wr = threadIdx.x >> 7, wc = (threadIdx.x >> 6) & 1;
  const int b0r = ridx[m0] >> 12;
#pragma unroll
  for (int ni = 0; ni < 4; ++ni) {
    const int col = n0 + wc * 64 + ni * 16 + l16;
    const float bcol = bias[col];
#pragma unroll
    for (int mi = 0; mi < 4; ++mi) {
      float v0 = 0.f, v1 = 0.f;
#pragma unroll
      for (int r = 0; r < 4; ++r) {
        const int row = m0 + wr * 64 + mi * 16 + quad * 4 + r;
        const float v = fmaxf(acc[mi][ni][r] + bcol, 0.f);
        const int b = ridx[row] >> 12;
        if (b == b0r) v0 += v; else v1 += v;
      }
      v0 += __shfl_xor(v0, 16, 64); v0 += __shfl_xor(v0, 32, 64);
      v1 += __shfl_xor(v1, 16, 64); v1 += __shfl_xor(v1, 32, 64);
      if (quad == 0) {
        atomicAdd(&red[b0r * 1024 + col], v0);
        if (b0r + 1 < 8 && v1 != 0.f) atomicAdd(&red[(b0r + 1) * 1024 + col], v1);
      }
    }
  }
}

// ---------------- kernel C: GEMM6 + fused zfix + fused s-dot + s_empty tail blocks ---------
__global__ __launch_bounds__(256, 2)
void kernelC(const bf16* __restrict__ zpre, const bf16* __restrict__ Ws2b,
             const float* __restrict__ bs2, const float* __restrict__ Ws3,
             const float* __restrict__ globv, const int* __restrict__ sics,
             float* __restrict__ sbuf,
             const float* __restrict__ Ws2, const float* __restrict__ bs3,
             float* __restrict__ semp, int nC)
{
  __shared__ alignas(16) bf16 lA[8192], lB[8192];
  if (blockIdx.x >= nC) {
    // -------- s_empty for batch b: wave-parallel, coalesced Ws2 reads (fp32 path) --------
    int b = blockIdx.x - nC, t = threadIdx.x;
    float* zrow = (float*)lA;       // 512 f32 (reuses GEMM LDS)
    float* wsum = (float*)lB;       // 4 f32
    zrow[t]       = fmaxf(globv[b * 512 + t], 0.f);
    zrow[t + 256] = fmaxf(globv[b * 512 + t + 256], 0.f);
    __syncthreads();
    int w = t >> 6, lane = t & 63;
    float ws = 0.f;
    for (int tt = w * 64; tt < w * 64 + 64; ++tt) {
      float a = 0.f;
#pragma unroll
      for (int oi = 0; oi < 8; ++oi) {
        int o = lane + oi * 64;
        a += zrow[o] * Ws2[(size_t)tt * 512 + o];
      }
      for (int off = 32; off; off >>= 1) a += __shfl_xor(a, off, 64);
      if (lane == 0) ws += fmaxf(a + bs2[tt], 0.f) * Ws3[tt];
    }
    if (lane == 0) wsum[w] = ws;
    __syncthreads();
    if (t == 0) semp[b] = wsum[0] + wsum[1] + wsum[2] + wsum[3] + bs3[0];
    return;
  }
  const int x = xcd_swz(blockIdx.x, nC);
  const int m0 = (x >> 1) * 128, n0 = (x & 1) * 128;
  const int tid  = threadIdx.x;
  const int lane = tid & 63, quad = lane >> 4, l16 = lane & 15;
  const int wr = tid >> 7, wc = (tid >> 6) & 1;
  const int srow = tid >> 2;
  const int scol = (tid & 3) << 3;

  // A-staging with fused zfix: z = relu(zpre + glob[b(row)])  (bit-identical to zfix path)
  const int r0g = m0 + srow, r1g = r0g + 64;
  const float* gv0 = globv + ((size_t)(sics[r0g] >> 12) << 9);
  const float* gv1 = globv + ((size_t)(sics[r1g] >> 12) << 9);
  const bf16* za0 = zpre + (size_t)r0g * 512 + scol;
  const bf16* za1 = zpre + (size_t)r1g * 512 + scol;
  // B-staging via global_load_lds
  const bf16* aB0 = Ws2b + (size_t)(n0 + srow) * 512 + scol;
  const bf16* aB1 = aB0 + (size_t)64 * 512;
  bf16* lB00 = lB + tid * 8;        bf16* lB01 = lB + 2048 + tid * 8;
  bf16* lB10 = lB + 4096 + tid * 8; bf16* lB11 = lB + 6144 + tid * 8;

  f32x4 acc[4][4];
  const f32x4 z4 = {0.f, 0.f, 0.f, 0.f};
#pragma unroll
  for (int i = 0; i < 4; ++i)
#pragma unroll
    for (int j = 0; j < 4; ++j) acc[i][j] = z4;

  auto stageA = [&](const bf16* src, const float* gv, int col, bf16* dst) {
    uint4 u = *(const uint4*)src;
    bf16 e[8]; *(uint4*)e = u;
    bf16 o[8];
#pragma unroll
    for (int i = 0; i < 8; ++i)
      o[i] = __float2bfloat16(fmaxf(__bfloat162float(e[i]) + gv[col + i], 0.f));
    *(uint4*)dst = *(uint4*)o;
  };

  for (int k = 0; k < 8; ++k) {
    const int k0 = k * 64;
    gld16(aB0 + k0, lB00);      gld16(aB1 + k0, lB01);
    gld16(aB0 + k0 + 32, lB10); gld16(aB1 + k0 + 32, lB11);
    stageA(za0 + k0,      gv0, k0 + scol,      lA + tid * 8);
    stageA(za1 + k0,      gv1, k0 + scol,      lA + 2048 + tid * 8);
    stageA(za0 + k0 + 32, gv0, k0 + scol + 32, lA + 4096 + tid * 8);
    stageA(za1 + k0 + 32, gv1, k0 + scol + 32, lA + 6144 + tid * 8);
    __syncthreads();
#pragma unroll
    for (int kk = 0; kk < 2; ++kk) {
      bf16x8v af[4], bfr[4];
#pragma unroll
      for (int i = 0; i < 4; ++i) {
        af[i]  = *(const bf16x8v*)&lA[kk * 4096 + (wr * 64 + i * 16 + l16) * 32 + quad * 8];
        bfr[i] = *(const bf16x8v*)&lB[kk * 4096 + (wc * 64 + i * 16 + l16) * 32 + quad * 8];
      }
#pragma unroll
      for (int mi = 0; mi < 4; ++mi)
#pragma unroll
        for (int ni = 0; ni < 4; ++ni)
          acc[mi][ni] = __builtin_amdgcn_mfma_f32_16x16x32_bf16(af[mi], bfr[ni], acc[mi][ni], 0, 0, 0);
    }
    __syncthreads();
  }

#pragma unroll
  for (int mi = 0; mi < 4; ++mi) {
#pragma unroll
    for (int r = 0; r < 4; ++r) {
      const int row = m0 + wr * 64 + mi * 16 + quad * 4 + r;
      float p = 0.f;
#pragma unroll
      for (int ni = 0; ni < 4; ++ni) {
        const int col = n0 + wc * 64 + ni * 16 + l16;
        p += fmaxf(acc[mi][ni][r] + bs2[col], 0.f) * Ws3[col];
      }
      p += __shfl_xor(p, 1, 64); p += __shfl_xor(p, 2, 64);
      p += __shfl_xor(p, 4, 64); p += __shfl_xor(p, 8, 64);
      if (l16 == 0) atomicAdd(&sbuf[row], p);
    }
  }
}

// glob[b][o] = bs1[o] + (iacc[b]/ns) . Ws1[o,528:1552] + (cacc[b]/nt) . Ws1[o,1552:2576]
__global__ __launch_bounds__(256) void glob_kernel(const float* __restrict__ iacc,
                                                   const float* __restrict__ cacc,
                                                   const int* __restrict__ cnt,
                                                   const float* __restrict__ Ws1,
                                                   const float* __restrict__ bs1,
                                                   float* __restrict__ globv) {
  int w    = (blockIdx.x * 256 + threadIdx.x) >> 6;  // 4096 waves
  int lane = threadIdx.x & 63;
  int b = w >> 9;
  int o = w & 511;
  const float* wi  = Ws1 + (size_t)o * 2576 + 528;
  const float* wcp = Ws1 + (size_t)o * 2576 + 1552;
  float a1 = 0.f, a2 = 0.f;
  for (int k = lane; k < 1024; k += 64) {
    a1 += iacc[b * 1024 + k] * wi[k];
    a2 += cacc[b * 1024 + k] * wcp[k];
  }
  for (int off = 32; off; off >>= 1) {
    a1 += __shfl_xor(a1, off, 64);
    a2 += __shfl_xor(a2, off, 64);
  }
  if (lane == 0) {
    float ns = (float)(cnt[b + 1] - cnt[b]);
    float nt = (float)(cnt[9 + b + 1] - cnt[9 + b]);
    globv[b * 512 + o] = bs1[o] + a1 / ns + a2 / nt;
  }
}

__global__ void scale_kernel(const float* __restrict__ sbuf,
                             const float* __restrict__ semp,
                             const int* __restrict__ cnt,
                             const float* __restrict__ bs3,
                             float* __restrict__ out4) {
  int i = blockIdx.x * 256 + threadIdx.x;   // 0..32767
  if (i >= 32768) return;
  int b = i >> 12, r = i & 4095;
  int base = cnt[b];
  int lim = cnt[b + 1] - base;
  float s = (r < lim) ? sbuf[base + r] + bs3[0] : semp[b];
  out4[i] = 1.f / (1.f + expf(-s)) - 0.5f;
}

// ---------------- host ----------------

extern "C" void kernel_launch(void* const* d_in, const int* in_sizes, int n_in,
                              void* d_out, int out_size, void* d_ws, size_t ws_size,
                              hipStream_t stream) {
  const float* geo = (const float*)d_in[0];
  const float* pcd = (const float*)d_in[1];
  const float* Wi1 = (const float*)d_in[2];
  const float* bi1 = (const float*)d_in[3];
  const float* Wi2 = (const float*)d_in[4];
  const float* bi2 = (const float*)d_in[5];
  const float* Wc1 = (const float*)d_in[6];
  const float* bc1 = (const float*)d_in[7];
  const float* Wc2 = (const float*)d_in[8];
  const float* bc2 = (const float*)d_in[9];
  const float* Ws1 = (const float*)d_in[10];
  const float* bs1 = (const float*)d_in[11];
  const float* Ws2 = (const float*)d_in[12];
  const float* bs2 = (const float*)d_in[13];
  const float* Ws3 = (const float*)d_in[14];
  const float* bs3 = (const float*)d_in[15];
  const int* sics = (const int*)d_in[18];
  const int* tics = (const int*)d_in[19];
  const int Ns = in_sizes[18];   // 23552 = 184*128
  const int Nt = in_sizes[19];   // 24704 = 193*128
  const int Ms = Ns / 128, Mt = Nt / 128;
  const int Nrows = Ns + Nt;

  float* out0 = (float*)d_out;                      // (8,4096,528)
  float* out1 = out0 + (size_t)8 * 4096 * 528;      // (8,4096,528)
  float* out2 = out1 + (size_t)8 * 4096 * 528;      // (8,4096,3)
  float* out3 = out2 + (size_t)8 * 4096 * 3;        // (8,4096,3)
  float* out4 = out3 + (size_t)8 * 4096 * 3;        // (8,1,4096)

  char* wp = (char*)d_ws;
  auto alloc = [&](size_t bytes) -> void* {
    void* p = (void*)wp;
    wp += (bytes + 255) & ~(size_t)255;
    return p;
  };
  int*   cnt   = (int*)  alloc(128);
  float* iacc  = (float*)alloc((size_t)8 * 1024 * 4);   // iacc/cacc/sbuf contiguous (zero job)
  float* cacc  = (float*)alloc((size_t)8 * 1024 * 4);
  float* sbuf  = (float*)alloc((size_t)Ns * 4);
  float* globb = (float*)alloc((size_t)8 * 512 * 4);
  float* semp  = (float*)alloc(64);
  bf16* Wi1b  = (bf16*)alloc((size_t)640  * 576 * 2);   // rows 528..639 uninit (cols discarded)
  bf16* Wi2b  = (bf16*)alloc((size_t)1024 * 576 * 2);
  bf16* Wc1b  = (bf16*)alloc((size_t)640  * 576 * 2);
  bf16* Wc2b  = (bf16*)alloc((size_t)1024 * 576 * 2);
  bf16* Ws1sb = (bf16*)alloc((size_t)512  * 576 * 2);
  bf16* Ws2b  = (bf16*)alloc((size_t)256  * 512 * 2);
  bf16* geo_b = (bf16*)alloc((size_t)Nrows * 576 * 2);
  bf16* big_s = (bf16*)alloc((size_t)Ns * 576 * 2);
  bf16* big_t = (bf16*)alloc((size_t)Nt * 576 * 2);
  bf16* zpre  = (bf16*)alloc((size_t)Ns * 512 * 2);

  float inv = 1.0f / sqrtf(528.0f);

  // ---- prep: weights + zero accs + geo_b conversion (4-row ILP) + maps ----
  PrepP P;
  {
    const float* srcs[6] = {Wi1, Wi2, Wc1, Wc2, Ws1, Ws2};
    bf16* dsts[6]        = {Wi1b, Wi2b, Wc1b, Wc2b, Ws1sb, Ws2b};
    int slds[6] = {528, 528, 528, 528, 2576, 512};
    int rows[6] = {528, 1024, 528, 1024, 512, 256};
    int Ks[6]   = {528, 528, 528, 528, 528, 512};
    int Kps[6]  = {576, 576, 576, 576, 576, 512};
    int nblk = 0;
    for (int i = 0; i < 6; ++i) {
      P.Wsrc[i] = srcs[i]; P.Wdst[i] = dsts[i]; P.sld[i] = slds[i];
      P.rows[i] = rows[i]; P.K[i] = Ks[i]; P.Kpad[i] = Kps[i];
      P.off[i] = nblk;
      nblk += (rows[i] * Kps[i] + 255) / 256;
    }
    P.off[6] = nblk;
    P.zbuf = iacc; P.ztotal = 8192 + 8192 + Ns;
    nblk += (P.ztotal + 255) / 256;
    P.off[7] = nblk;
    P.geo = geo; P.geo_b = geo_b; P.Nrows = Nrows;
    P.Q = (Nrows + 3) >> 2;
    nblk += (P.Q * 72 + 255) / 256;
    P.off[8] = nblk;
    P.sics = sics; P.tics = tics; P.Ns = Ns; P.Nt = Nt; P.cnt = cnt;
    int n = Ns > Nt ? Ns : Nt;
    nblk += (n + 255) / 256;
    P.off[9] = nblk;
    prep_kernel<<<dim3(nblk), dim3(256), 0, stream>>>(P);
  }

  // ---- kernel A: src panels (L1 + zpre co-located), tgt L1 (XCD-swizzled) ----
  kernelA<<<dim3(Ms * 9 + Mt * 5), dim3(256), 0, stream>>>(
      geo_b, Wi1b, Wc1b, Ws1sb, bi1, bc1, big_s, big_t, zpre, Ms, Mt);

  // ---- kernel B: L2-src, L2-tgt (batch sums, XCD-swizzled) + output fills at tail ----
  kernelB<<<dim3(Ms * 8 + Mt * 8 + 16384), dim3(256), 0, stream>>>(
      big_s, big_t, Wi2b, Wc2b, bi2, bc2, iacc, cacc, sics, tics, Ms, Mt,
      geo, pcd, cnt, out0, out1, out2, out3, Ns, inv);

  glob_kernel<<<dim3(1024), dim3(256), 0, stream>>>(iacc, cacc, cnt, Ws1, bs1, globb);
  // kernel C: GEMM6 + fused zfix + s-dot, with s_empty as 8 tail blocks
  kernelC<<<dim3(Ms * 2 + 8), dim3(256), 0, stream>>>(
      zpre, Ws2b, bs2, Ws3, globb, sics, sbuf, Ws2, bs3, semp, Ms * 2);
  scale_kernel<<<dim3(128), dim3(256), 0, stream>>>(sbuf, semp, cnt, bs3, out4);
}